// Round 1
// baseline (632.091 us; speedup 1.0000x reference)
//
#include <hip/hip_runtime.h>

typedef float f4 __attribute__((ext_vector_type(4)));

#define NN 4096
#define DD 64
#define SS 4
#define COPY_OFF 67108864LL   // 4*4096*4096
#define OUT_TOTAL 134217728LL // 2*4*4096*4096
#define T_ELEMS 1048576       // 4*4096*64

// ---------------- Kernel 1: T[row][e] = sum_d x1[row][d] * W[d][e] ----------------
// rows = S*N = 16384 flat. Each block: 4 rows, W staged in LDS.
__global__ __launch_bounds__(256) void compute_T_kernel(
    const float* __restrict__ x1, const float* __restrict__ W, float* __restrict__ T)
{
    __shared__ float Ws[64 * 64];
    __shared__ float x1s[4 * 64];
    int t = threadIdx.x;
#pragma unroll
    for (int r = 0; r < 4; ++r) {
        int f = t + 256 * r;
        reinterpret_cast<f4*>(Ws)[f] = reinterpret_cast<const f4*>(W)[f];
    }
    long long rowbase = (long long)blockIdx.x * 4;
    if (t < 64)
        reinterpret_cast<f4*>(x1s)[t] =
            reinterpret_cast<const f4*>(x1 + rowbase * 64)[t];
    __syncthreads();
    int rr = t >> 6, e = t & 63;
    float acc = 0.f;
#pragma unroll
    for (int d = 0; d < 64; ++d)
        acc = fmaf(x1s[rr * 64 + d], Ws[d * 64 + e], acc);
    T[(rowbase + rr) * 64 + e] = acc;  // coalesced
}

// ---------------- Kernel 2: out[s,i,j] = sum_e T[s,i,e] * x0[s,j,e] + bias --------
// 128x128 tile / block, 256 threads, 8x8 microtile, K=64 single pass.
// LDS k-major [64][128] with XOR swizzle pos = k*128 + (i ^ (k&28)):
//   - staging writes: 2-way bank conflict (free)
//   - frag reads: ds_read_b128, A broadcast across 16 lanes, B at data floor
__global__ __launch_bounds__(256) void bilin_gemm_kernel(
    const float* __restrict__ T, const float* __restrict__ x0,
    const float* __restrict__ bias_p, float* __restrict__ out, int skip_tail)
{
    __shared__ float As[64 * 128];
    __shared__ float Bs[64 * 128];
    int t = threadIdx.x;
    int bid = blockIdx.x;
    int jt = bid & 31, it = (bid >> 5) & 31, s = bid >> 10;
    int i0 = it * 128, j0 = jt * 128;
    const float* Ta = T  + ((long long)(s * NN + i0) << 6);
    const float* Xa = x0 + ((long long)(s * NN + j0) << 6);

#pragma unroll
    for (int r = 0; r < 8; ++r) {
        int f = t + 256 * r;       // 2048 float4s per tile
        int ii = f >> 4;           // row within tile (0..127)
        int k0 = (f & 15) << 2;    // k base (0..60)
        f4 va = *reinterpret_cast<const f4*>(Ta + ii * 64 + k0);
        f4 vb = *reinterpret_cast<const f4*>(Xa + ii * 64 + k0);
#pragma unroll
        for (int q = 0; q < 4; ++q) {
            int k = k0 + q;
            int pos = (k << 7) + (ii ^ (k & 28));
            As[pos] = va[q];
            Bs[pos] = vb[q];
        }
    }
    __syncthreads();

    int tx = t & 15, ty = t >> 4;
    float acc[8][8];
#pragma unroll
    for (int m = 0; m < 8; ++m)
#pragma unroll
        for (int n = 0; n < 8; ++n) acc[m][n] = 0.f;

#pragma unroll 8
    for (int k = 0; k < 64; ++k) {
        int swz = k & 28;
        int kb = k << 7;
        f4 a0 = *reinterpret_cast<const f4*>(&As[kb + ((ty * 8) ^ swz)]);
        f4 a1 = *reinterpret_cast<const f4*>(&As[kb + ((ty * 8 + 4) ^ swz)]);
        f4 b0 = *reinterpret_cast<const f4*>(&Bs[kb + ((tx * 8) ^ swz)]);
        f4 b1 = *reinterpret_cast<const f4*>(&Bs[kb + ((tx * 8 + 4) ^ swz)]);
        float a[8], b[8];
        *reinterpret_cast<f4*>(a) = a0; *reinterpret_cast<f4*>(a + 4) = a1;
        *reinterpret_cast<f4*>(b) = b0; *reinterpret_cast<f4*>(b + 4) = b1;
#pragma unroll
        for (int m = 0; m < 8; ++m)
#pragma unroll
            for (int n = 0; n < 8; ++n)
                acc[m][n] = fmaf(a[m], b[n], acc[m][n]);
    }

    float bias = bias_p[0];
    bool skip = skip_tail && (s == 3) && (i0 >= 3840);
#pragma unroll
    for (int m = 0; m < 8; ++m) {
        int row = i0 + ty * 8 + m;
        long long o0 = ((long long)(s * NN + row) << 12) + j0 + tx * 8;
        f4 c0 = { acc[m][0] + bias, acc[m][1] + bias, acc[m][2] + bias, acc[m][3] + bias };
        f4 c1 = { acc[m][4] + bias, acc[m][5] + bias, acc[m][6] + bias, acc[m][7] + bias };
        __builtin_nontemporal_store(c0, reinterpret_cast<f4*>(out + o0));
        __builtin_nontemporal_store(c1, reinterpret_cast<f4*>(out + o0 + 4));
        if (!skip) {
            __builtin_nontemporal_store(c0, reinterpret_cast<f4*>(out + o0 + COPY_OFF));
            __builtin_nontemporal_store(c1, reinterpret_cast<f4*>(out + o0 + COPY_OFF + 4));
        }
    }
}

// Fallback fixup: copy the T-scratch region (copy-1, s=3, rows 3840..4095)
// from the identical copy-0 region.
__global__ __launch_bounds__(256) void fixup_kernel(float* __restrict__ out)
{
    int idx = blockIdx.x * 256 + threadIdx.x;  // 262144 float4s
    const f4* src = reinterpret_cast<const f4*>(out + 66060288LL); // copy0 s=3 row 3840
    f4* dst = reinterpret_cast<f4*>(out + (OUT_TOTAL - T_ELEMS));
    dst[idx] = src[idx];
}

extern "C" void kernel_launch(void* const* d_in, const int* in_sizes, int n_in,
                              void* d_out, int out_size, void* d_ws, size_t ws_size,
                              hipStream_t stream)
{
    const float* x0   = (const float*)d_in[0];  // tensor0 (S,N,D)
    const float* x1   = (const float*)d_in[1];  // tensor1 (S,N,D)
    const float* W    = (const float*)d_in[2];  // kernel (D,D)
    const float* bias = (const float*)d_in[3];  // scalar

    float* out = (float*)d_out;
    bool use_ws = ws_size >= (size_t)T_ELEMS * sizeof(float);
    float* T = use_ws ? (float*)d_ws : out + (OUT_TOTAL - T_ELEMS);

    compute_T_kernel<<<4096, 256, 0, stream>>>(x1, W, T);
    bilin_gemm_kernel<<<4096, 256, 0, stream>>>(T, x0, bias, out, use_ws ? 0 : 1);
    if (!use_ws)
        fixup_kernel<<<1024, 256, 0, stream>>>(out);
}

// Round 2
// 552.615 us; speedup vs baseline: 1.1438x; 1.1438x over previous
//
#include <hip/hip_runtime.h>

typedef float f4 __attribute__((ext_vector_type(4)));

#define NN 4096
#define DD 64
#define SS 4
#define COPY_OFF 67108864LL   // 4*4096*4096
#define OUT_TOTAL 134217728LL // 2*4*4096*4096
#define T_ELEMS 1048576       // 4*4096*64

// ---------------- Kernel 1: T[row][e] = sum_d x1[row][d] * W[d][e] ----------------
__global__ __launch_bounds__(256) void compute_T_kernel(
    const float* __restrict__ x1, const float* __restrict__ W, float* __restrict__ T)
{
    __shared__ float Ws[64 * 64];
    __shared__ float x1s[4 * 64];
    int t = threadIdx.x;
#pragma unroll
    for (int r = 0; r < 4; ++r) {
        int f = t + 256 * r;
        reinterpret_cast<f4*>(Ws)[f] = reinterpret_cast<const f4*>(W)[f];
    }
    long long rowbase = (long long)blockIdx.x * 4;
    if (t < 64)
        reinterpret_cast<f4*>(x1s)[t] =
            reinterpret_cast<const f4*>(x1 + rowbase * 64)[t];
    __syncthreads();
    int rr = t >> 6, e = t & 63;
    float acc = 0.f;
#pragma unroll
    for (int d = 0; d < 64; ++d)
        acc = fmaf(x1s[rr * 64 + d], Ws[d * 64 + e], acc);
    T[(rowbase + rr) * 64 + e] = acc;  // coalesced
}

// ---------------- Kernel 2: out[s,i,j] = sum_e T[s,i,e] * x0[s,j,e] + bias --------
// 128x128 tile / block, 512 threads (8 waves -> 4 waves/SIMD at 2 blocks/CU),
// microtile 4 rows x 8 cols, cols = tx*4 + h*64.
// LDS k-major [64][128], XOR swizzle pos = k*128 + (i ^ (k&28)):
//   staging scalar writes: 2-way (free); A-reads: 4 distinct b128, broadcast,
//   conflict-free; B-reads: 16 contiguous b128 = 2 words/bank, conflict-free.
// Stores: each instruction writes 16 consecutive lanes x 16 B (fully dense).
__global__ __launch_bounds__(512, 4) void bilin_gemm_kernel(
    const float* __restrict__ T, const float* __restrict__ x0,
    const float* __restrict__ bias_p, float* __restrict__ out, int skip_tail)
{
    __shared__ float As[64 * 128];
    __shared__ float Bs[64 * 128];
    int t = threadIdx.x;
    int bid = blockIdx.x;
    int jt = bid & 31, it = (bid >> 5) & 31, s = bid >> 10;
    int i0 = it * 128, j0 = jt * 128;
    const float* Ta = T  + ((long long)(s * NN + i0) << 6);
    const float* Xa = x0 + ((long long)(s * NN + j0) << 6);

    // Stage both tiles: 2048 f4 each, 512 threads -> 4 f4 per thread per tile.
#pragma unroll
    for (int r = 0; r < 4; ++r) {
        int f = t + 512 * r;       // 0..2047
        int ii = f >> 4;           // row within tile (0..127)
        int k0 = (f & 15) << 2;    // k base (0..60)
        f4 va = *reinterpret_cast<const f4*>(Ta + ii * 64 + k0);
        f4 vb = *reinterpret_cast<const f4*>(Xa + ii * 64 + k0);
#pragma unroll
        for (int q = 0; q < 4; ++q) {
            int k = k0 + q;
            int pos = (k << 7) + (ii ^ (k & 28));
            As[pos] = va[q];
            Bs[pos] = vb[q];
        }
    }
    __syncthreads();

    int tx = t & 15, ty = t >> 4;   // ty in [0,32)
    float acc[4][8];
#pragma unroll
    for (int m = 0; m < 4; ++m)
#pragma unroll
        for (int n = 0; n < 8; ++n) acc[m][n] = 0.f;

#pragma unroll 4
    for (int k = 0; k < 64; ++k) {
        int swz = k & 28;
        int kb = k << 7;
        f4 a  = *reinterpret_cast<const f4*>(&As[kb + ((ty * 4) ^ swz)]);
        int bo = (tx * 4) ^ swz;
        f4 b0 = *reinterpret_cast<const f4*>(&Bs[kb + bo]);
        f4 b1 = *reinterpret_cast<const f4*>(&Bs[kb + bo + 64]);
        float b[8];
        *reinterpret_cast<f4*>(b) = b0; *reinterpret_cast<f4*>(b + 4) = b1;
#pragma unroll
        for (int m = 0; m < 4; ++m)
#pragma unroll
            for (int n = 0; n < 8; ++n)
                acc[m][n] = fmaf(a[m], b[n], acc[m][n]);
    }

    float bias = bias_p[0];
    bool skip = skip_tail && (s == 3) && (i0 >= 3840);
#pragma unroll
    for (int m = 0; m < 4; ++m) {
        int row = i0 + ty * 4 + m;
        long long o0 = ((long long)(s * NN + row) << 12) + j0 + tx * 4;
        f4 c0 = { acc[m][0] + bias, acc[m][1] + bias, acc[m][2] + bias, acc[m][3] + bias };
        f4 c1 = { acc[m][4] + bias, acc[m][5] + bias, acc[m][6] + bias, acc[m][7] + bias };
        __builtin_nontemporal_store(c0, reinterpret_cast<f4*>(out + o0));
        __builtin_nontemporal_store(c1, reinterpret_cast<f4*>(out + o0 + 64));
        if (!skip) {
            __builtin_nontemporal_store(c0, reinterpret_cast<f4*>(out + o0 + COPY_OFF));
            __builtin_nontemporal_store(c1, reinterpret_cast<f4*>(out + o0 + COPY_OFF + 64));
        }
    }
}

// Fallback fixup: copy the T-scratch region (copy-1, s=3, rows 3840..4095)
// from the identical copy-0 region.
__global__ __launch_bounds__(256) void fixup_kernel(float* __restrict__ out)
{
    int idx = blockIdx.x * 256 + threadIdx.x;  // 262144 float4s
    const f4* src = reinterpret_cast<const f4*>(out + 66060288LL); // copy0 s=3 row 3840
    f4* dst = reinterpret_cast<f4*>(out + (OUT_TOTAL - T_ELEMS));
    dst[idx] = src[idx];
}

extern "C" void kernel_launch(void* const* d_in, const int* in_sizes, int n_in,
                              void* d_out, int out_size, void* d_ws, size_t ws_size,
                              hipStream_t stream)
{
    const float* x0   = (const float*)d_in[0];  // tensor0 (S,N,D)
    const float* x1   = (const float*)d_in[1];  // tensor1 (S,N,D)
    const float* W    = (const float*)d_in[2];  // kernel (D,D)
    const float* bias = (const float*)d_in[3];  // scalar

    float* out = (float*)d_out;
    bool use_ws = ws_size >= (size_t)T_ELEMS * sizeof(float);
    float* T = use_ws ? (float*)d_ws : out + (OUT_TOTAL - T_ELEMS);

    compute_T_kernel<<<4096, 256, 0, stream>>>(x1, W, T);
    bilin_gemm_kernel<<<4096, 512, 0, stream>>>(T, x0, bias, out, use_ws ? 0 : 1);
    if (!use_ws)
        fixup_kernel<<<1024, 256, 0, stream>>>(out);
}